// Round 4
// baseline (187.114 us; speedup 1.0000x reference)
//
#include <hip/hip_runtime.h>
#include <cstdint>

// Problem constants
#define N_TOK 4096   // B*T
#define D_    1024
#define E_    8
#define I_    512
#define KTOP  2
#define BM    64     // position-tile (expert segments padded to BM)
#define BK    64     // K-step
#define CAP   (N_TOK*KTOP + E_*BM)   // 8704 max padded positions
#define WSZ   ((size_t)E_ * I_ * D_) // one weight's element count

typedef __attribute__((ext_vector_type(4))) float f32x4;
typedef __attribute__((ext_vector_type(8))) short bf16x8;

__device__ inline unsigned short f2bf(float f) {
  union { float f; uint32_t u; } v; v.f = f;
  uint32_t r = v.u + 0x7fffu + ((v.u >> 16) & 1u);
  return (unsigned short)(r >> 16);
}

#define GLOAD_LDS16(gp, lp)                                                        \
  __builtin_amdgcn_global_load_lds((const __attribute__((address_space(1))) void*)(gp), \
                                   (__attribute__((address_space(3))) void*)(lp), 16, 0, 0)

// one sync point per K-step: own vmcnt(0) -> barrier (fenced against scheduler motion)
#define KSYNC                                                   \
  do {                                                          \
    __builtin_amdgcn_sched_barrier(0);                          \
    asm volatile("s_waitcnt vmcnt(0)" ::: "memory");            \
    __builtin_amdgcn_s_barrier();                               \
    __builtin_amdgcn_sched_barrier(0);                          \
  } while (0)

// ---------------- fp32 -> bf16 convert: all 3 weights in one launch ----------------
__global__ __launch_bounds__(256) void convertw_kernel(const float* __restrict__ wg,
                                                       const float* __restrict__ wu,
                                                       const float* __restrict__ wd,
                                                       unsigned short* __restrict__ dst) {
  const int y = blockIdx.y;
  const float* s = (y == 0) ? wg : (y == 1) ? wu : wd;
  unsigned short* d = dst + (size_t)y * WSZ;
  int i = blockIdx.x * 256 + threadIdx.x;
  const float4 v = reinterpret_cast<const float4*>(s)[i];
  ushort4 o;
  o.x = f2bf(v.x); o.y = f2bf(v.y); o.z = f2bf(v.z); o.w = f2bf(v.w);
  reinterpret_cast<ushort4*>(d)[i] = o;
}

// ---------------- router: logits (fp32), top-2, softmax; fused x->bf16 ----------------
__global__ __launch_bounds__(256) void router_kernel(const float* __restrict__ x,
                                                     const float* __restrict__ rw,
                                                     float* __restrict__ logits,
                                                     int* __restrict__ sel,
                                                     float* __restrict__ prob,
                                                     unsigned short* __restrict__ Xb) {
  const int lane = threadIdx.x & 63;
  const int tok  = blockIdx.x * 4 + (threadIdx.x >> 6);
  const float4* xr = reinterpret_cast<const float4*>(x + (size_t)tok * D_);
  float4 xv[4];
#pragma unroll
  for (int q = 0; q < 4; ++q) xv[q] = xr[q * 64 + lane];
  float acc[E_];
#pragma unroll
  for (int e = 0; e < E_; ++e) {
    const float4* wr = reinterpret_cast<const float4*>(rw + (size_t)e * D_);
    float s = 0.f;
#pragma unroll
    for (int q = 0; q < 4; ++q) {
      float4 wv = wr[q * 64 + lane];
      s += xv[q].x * wv.x + xv[q].y * wv.y + xv[q].z * wv.z + xv[q].w * wv.w;
    }
    acc[e] = s;
  }
  ushort4* xb = reinterpret_cast<ushort4*>(Xb + (size_t)tok * D_);
#pragma unroll
  for (int q = 0; q < 4; ++q) {
    ushort4 o;
    o.x = f2bf(xv[q].x); o.y = f2bf(xv[q].y); o.z = f2bf(xv[q].z); o.w = f2bf(xv[q].w);
    xb[q * 64 + lane] = o;
  }
#pragma unroll
  for (int e = 0; e < E_; ++e)
#pragma unroll
    for (int off = 32; off; off >>= 1) acc[e] += __shfl_xor(acc[e], off);
  if (lane == 0) {
    float v0 = -1e30f, v1 = -1e30f; int i0 = 0, i1 = 0;
#pragma unroll
    for (int e = 0; e < E_; ++e) {
      float v = acc[e];
      logits[(size_t)tok * E_ + e] = v;
      if (v > v0)      { v1 = v0; i1 = i0; v0 = v; i0 = e; }
      else if (v > v1) { v1 = v;  i1 = e; }
    }
    float t  = __expf(v1 - v0);
    sel[tok * 2] = i0; sel[tok * 2 + 1] = i1;
    prob[tok * 2] = 1.f / (1.f + t);
    prob[tok * 2 + 1] = t / (1.f + t);
  }
}

// ---------------- plan: counts (ballot), padded offsets, scatter, pads, zbuf ----------------
__global__ __launch_bounds__(1024) void plan_kernel(const int* __restrict__ sel,
                                                    const float* __restrict__ prob,
                                                    int* __restrict__ offs,
                                                    int* __restrict__ ptok,
                                                    float* __restrict__ pprob,
                                                    unsigned int* __restrict__ zbuf) {
  __shared__ int wcnt[16][E_];
  __shared__ int pfx[16][E_];
  __shared__ int soffs[E_ + 1];
  __shared__ int secnt[E_];
  const int tid = threadIdx.x;
  const int wave = tid >> 6, lane = tid & 63;
  const unsigned long long lt = (1ull << lane) - 1ull;

  zbuf[tid] = 0u;   // 4KB of zeros for gemm1 pad rows

  int   mye[8];
  int   mylp[8];
  float myp[8];
  int run[E_];
#pragma unroll
  for (int e = 0; e < E_; ++e) run[e] = 0;

#pragma unroll
  for (int it = 0; it < 8; ++it) {
    int i = wave * 512 + it * 64 + lane;
    int e = sel[i];
    mye[it] = e;
    myp[it] = prob[i];
    int lp = 0;
#pragma unroll
    for (int ee = 0; ee < E_; ++ee) {
      unsigned long long m = __ballot(e == ee);
      if (e == ee) lp = run[ee] + __popcll(m & lt);
      run[ee] += __popcll(m);
    }
    mylp[it] = lp;
  }
#pragma unroll
  for (int ee = 0; ee < E_; ++ee)
    if (lane == ee) wcnt[wave][ee] = run[ee];
  __syncthreads();

  if (tid == 0) {
    int ro = 0;
#pragma unroll
    for (int e = 0; e < E_; ++e) {
      int c = 0;
      int r = ro;
      for (int w = 0; w < 16; ++w) { pfx[w][e] = r; r += wcnt[w][e]; c += wcnt[w][e]; }
      soffs[e] = ro; offs[e] = ro; secnt[e] = c;
      ro += (c + BM - 1) & ~(BM - 1);
    }
    soffs[E_] = ro; offs[E_] = ro;
  }
  __syncthreads();

#pragma unroll
  for (int it = 0; it < 8; ++it) {
    int i = wave * 512 + it * 64 + lane;
    int pos = pfx[wave][mye[it]] + mylp[it];
    ptok[pos]  = i >> 1;
    pprob[pos] = myp[it];
  }
#pragma unroll
  for (int e = 0; e < E_; ++e) {
    int s = soffs[e] + secnt[e];
    int npad = soffs[e + 1] - s;
    if (tid < npad) ptok[s + tid] = -1;
  }
}

// ---------------- GEMM1: H = silu(X Wg^T) * (X Wu^T) ----------------
// 64x64 tile, BK=64, dbuf 48KB (3 blocks/CU), XCD-chunked y-inner grid decode.
__global__ __launch_bounds__(256) void gemm1_kernel(const unsigned short* __restrict__ Xb,
                                                    const unsigned short* __restrict__ Wg,
                                                    const unsigned short* __restrict__ Wu,
                                                    const int* __restrict__ ptok,
                                                    const int* __restrict__ offs,
                                                    const unsigned short* __restrict__ zbuf,
                                                    unsigned short* __restrict__ H) {
  __shared__ unsigned short As[2][BM * BK];
  __shared__ unsigned short Bg[2][BM * BK];
  __shared__ unsigned short Bu[2][BM * BK];
  __shared__ int toks[BM];

  // XCD-chunked decode: NB=1088, 136/XCD; within chunk y (N-panel) is fast dim
  const int flat = (blockIdx.x & 7) * 136 + (blockIdx.x >> 3);
  const int bx = flat >> 3;          // 0..135 : position tile
  const int by = flat & 7;           // 0..7   : I-panel (64 cols)

  const int total = offs[E_];
  const int t0 = bx * BM;
  if (t0 >= total) return;
  int e = 0;
#pragma unroll
  for (int i = 1; i < E_; ++i) if (offs[i] <= t0) e = i;

  const int tid  = threadIdx.x;
  const int lane = tid & 63;
  const int w    = tid >> 6;
  if (tid < BM) toks[tid] = ptok[t0 + tid];
  __syncthreads();

  const int ib    = by * 64;
  const int gcol8 = (lane & 7) ^ (lane >> 3);  // pre-swizzled source column (16B units)

  const unsigned short* asrc[2];
#pragma unroll
  for (int i = 0; i < 2; ++i) {
    int r = (w * 2 + i) * 8 + (lane >> 3);
    int t = toks[r];
    asrc[i] = (t >= 0) ? (Xb + (size_t)t * D_ + gcol8 * 8) : zbuf;
  }
  const unsigned short* bgsrc[2];
  const unsigned short* busrc[2];
#pragma unroll
  for (int i = 0; i < 2; ++i) {
    int r = (w * 2 + i) * 8 + (lane >> 3);
    size_t rowoff = ((size_t)e * I_ + ib + r) * D_ + gcol8 * 8;
    bgsrc[i] = Wg + rowoff;
    busrc[i] = Wu + rowoff;
  }

  f32x4 accg[2][2], accu[2][2];
#pragma unroll
  for (int m = 0; m < 2; ++m)
#pragma unroll
    for (int n = 0; n < 2; ++n) {
      accg[m][n] = (f32x4){0.f, 0.f, 0.f, 0.f};
      accu[m][n] = (f32x4){0.f, 0.f, 0.f, 0.f};
    }

  const int wr = w >> 1, wc = w & 1;
  const int xr7 = lane & 7;

#define STAGE1(p, k0)                                                          \
  do {                                                                         \
    _Pragma("unroll") for (int i = 0; i < 2; ++i) {                            \
      GLOAD_LDS16(asrc[i] + (k0), &As[p][(w * 2 + i) * 512]);                  \
      GLOAD_LDS16(bgsrc[i] + (k0), &Bg[p][(w * 2 + i) * 512]);                 \
      GLOAD_LDS16(busrc[i] + (k0), &Bu[p][(w * 2 + i) * 512]);                 \
    }                                                                          \
  } while (0)

#define COMPUTE1(p)                                                            \
  do {                                                                         \
    _Pragma("unroll") for (int kk = 0; kk < 2; ++kk) {                         \
      const int uoff = ((kk * 4 + (lane >> 4)) ^ xr7) * 8;                     \
      bf16x8 a[2], bg[2], bu[2];                                               \
      _Pragma("unroll") for (int m = 0; m < 2; ++m) {                          \
        int row = wr * 32 + m * 16 + (lane & 15);                              \
        a[m] = *reinterpret_cast<const bf16x8*>(&As[p][row * BK + uoff]);      \
      }                                                                        \
      _Pragma("unroll") for (int n = 0; n < 2; ++n) {                          \
        int row = wc * 32 + n * 16 + (lane & 15);                              \
        bg[n] = *reinterpret_cast<const bf16x8*>(&Bg[p][row * BK + uoff]);     \
        bu[n] = *reinterpret_cast<const bf16x8*>(&Bu[p][row * BK + uoff]);     \
      }                                                                        \
      __builtin_amdgcn_s_setprio(1);                                           \
      _Pragma("unroll") for (int m = 0; m < 2; ++m)                            \
        _Pragma("unroll") for (int n = 0; n < 2; ++n) {                        \
          accg[m][n] = __builtin_amdgcn_mfma_f32_16x16x32_bf16(bg[n], a[m], accg[m][n], 0, 0, 0); \
          accu[m][n] = __builtin_amdgcn_mfma_f32_16x16x32_bf16(bu[n], a[m], accu[m][n], 0, 0, 0); \
        }                                                                      \
      __builtin_amdgcn_s_setprio(0);                                           \
    }                                                                          \
  } while (0)

  STAGE1(0, 0);
  int t = 0;
  for (; t + 2 < D_ / BK; t += 2) {
    KSYNC; STAGE1(1, (t + 1) * BK); COMPUTE1(0);
    KSYNC; STAGE1(0, (t + 2) * BK); COMPUTE1(1);
  }
  KSYNC; STAGE1(1, (t + 1) * BK); COMPUTE1(0);
  KSYNC;                          COMPUTE1(1);

  // swapped-operand C/D layout: token = lane&15, N-index = (lane>>4)*4 + reg
#pragma unroll
  for (int m = 0; m < 2; ++m) {
    const int trow = wr * 32 + m * 16 + (lane & 15);
#pragma unroll
    for (int n = 0; n < 2; ++n) {
      const int icb = ib + wc * 32 + n * 16 + (lane >> 4) * 4;
      ushort4 st;
      float g, uu, h;
      g = accg[m][n][0]; uu = accu[m][n][0]; h = (g / (1.f + __expf(-g))) * uu; st.x = f2bf(h);
      g = accg[m][n][1]; uu = accu[m][n][1]; h = (g / (1.f + __expf(-g))) * uu; st.y = f2bf(h);
      g = accg[m][n][2]; uu = accu[m][n][2]; h = (g / (1.f + __expf(-g))) * uu; st.z = f2bf(h);
      g = accg[m][n][3]; uu = accu[m][n][3]; h = (g / (1.f + __expf(-g))) * uu; st.w = f2bf(h);
      *reinterpret_cast<ushort4*>(&H[(size_t)(t0 + trow) * I_ + icb]) = st;
    }
  }
#undef STAGE1
#undef COMPUTE1
}

// ---------------- GEMM2: out[token] += prob * (H Wd^T) ----------------
// 64x128 tile, BK=64, dbuf 48KB (3 blocks/CU), XCD-chunked y-inner grid decode.
__global__ __launch_bounds__(256) void gemm2_kernel(const unsigned short* __restrict__ H,
                                                    const unsigned short* __restrict__ Wd,
                                                    const int* __restrict__ ptok,
                                                    const float* __restrict__ pprob,
                                                    const int* __restrict__ offs,
                                                    float* __restrict__ out) {
  __shared__ unsigned short As[2][BM * BK];
  __shared__ unsigned short Bs[2][128 * BK];
  __shared__ int   toks[BM];
  __shared__ float probs[BM];

  const int flat = (blockIdx.x & 7) * 136 + (blockIdx.x >> 3);
  const int bx = flat >> 3;          // 0..135 : position tile
  const int by = flat & 7;           // 0..7   : D-panel (128 cols)

  const int total = offs[E_];
  const int t0 = bx * BM;
  if (t0 >= total) return;
  int e = 0;
#pragma unroll
  for (int i = 1; i < E_; ++i) if (offs[i] <= t0) e = i;

  const int tid  = threadIdx.x;
  const int lane = tid & 63;
  const int w    = tid >> 6;
  if (tid < BM) { toks[tid] = ptok[t0 + tid]; probs[tid] = pprob[t0 + tid]; }
  __syncthreads();

  const int db    = by * 128;
  const int gcol8 = (lane & 7) ^ (lane >> 3);

  const unsigned short* asrc[2];
#pragma unroll
  for (int i = 0; i < 2; ++i) {
    int r = (w * 2 + i) * 8 + (lane >> 3);
    asrc[i] = H + (size_t)(t0 + r) * I_ + gcol8 * 8;
  }
  const unsigned short* bsrc[4];
#pragma unroll
  for (int i = 0; i < 4; ++i) {
    int r = (w * 4 + i) * 8 + (lane >> 3);
    bsrc[i] = Wd + ((size_t)e * D_ + db + r) * I_ + gcol8 * 8;
  }

  f32x4 acc[2][4];
#pragma unroll
  for (int m = 0; m < 2; ++m)
#pragma unroll
    for (int n = 0; n < 4; ++n) acc[m][n] = (f32x4){0.f, 0.f, 0.f, 0.f};

  const int wr = w >> 1, wc = w & 1;
  const int xr7 = lane & 7;

#define STAGE2(p, k0)                                                          \
  do {                                                                         \
    _Pragma("unroll") for (int i = 0; i < 2; ++i)                              \
        GLOAD_LDS16(asrc[i] + (k0), &As[p][(w * 2 + i) * 512]);                \
    _Pragma("unroll") for (int i = 0; i < 4; ++i)                              \
        GLOAD_LDS16(bsrc[i] + (k0), &Bs[p][(w * 4 + i) * 512]);                \
  } while (0)

#define COMPUTE2(p)                                                            \
  do {                                                                         \
    _Pragma("unroll") for (int kk = 0; kk < 2; ++kk) {                         \
      const int uoff = ((kk * 4 + (lane >> 4)) ^ xr7) * 8;                     \
      bf16x8 a[2], b[4];                                                       \
      _Pragma("unroll") for (int m = 0; m < 2; ++m) {                          \
        int row = wr * 32 + m * 16 + (lane & 15);                              \
        a[m] = *reinterpret_cast<const bf16x8*>(&As[p][row * BK + uoff]);      \
      }                                                                        \
      _Pragma("unroll") for (int n = 0; n < 4; ++n) {                          \
        int row = wc * 64 + n * 16 + (lane & 15);                              \
        b[n] = *reinterpret_cast<const bf16x8*>(&Bs[p][row * BK + uoff]);      \
      }                                                                        \
      __builtin_amdgcn_s_setprio(1);                                           \
      _Pragma("unroll") for (int m = 0; m < 2; ++m)                            \
        _Pragma("unroll") for (int n = 0; n < 4; ++n)                          \
          acc[m][n] = __builtin_amdgcn_mfma_f32_16x16x32_bf16(b[n], a[m], acc[m][n], 0, 0, 0); \
      __builtin_amdgcn_s_setprio(0);                                           \
    }                                                                          \
  } while (0)

  STAGE2(0, 0);
  int t = 0;
  for (; t + 2 < I_ / BK; t += 2) {
    KSYNC; STAGE2(1, (t + 1) * BK); COMPUTE2(0);
    KSYNC; STAGE2(0, (t + 2) * BK); COMPUTE2(1);
  }
  KSYNC; STAGE2(1, (t + 1) * BK); COMPUTE2(0);
  KSYNC;                          COMPUTE2(1);

#pragma unroll
  for (int m = 0; m < 2; ++m) {
    const int trow = wr * 32 + m * 16 + (lane & 15);
    const int tk = toks[trow];
    const float p = probs[trow];
    if (tk >= 0) {
#pragma unroll
      for (int n = 0; n < 4; ++n) {
        const int dcb = db + wc * 64 + n * 16 + (lane >> 4) * 4;
        float* op = out + (size_t)tk * D_ + dcb;
        atomicAdd(op + 0, acc[m][n][0] * p);
        atomicAdd(op + 1, acc[m][n][1] * p);
        atomicAdd(op + 2, acc[m][n][2] * p);
        atomicAdd(op + 3, acc[m][n][3] * p);
      }
    }
  }
#undef STAGE2
#undef COMPUTE2
}

extern "C" void kernel_launch(void* const* d_in, const int* in_sizes, int n_in,
                              void* d_out, int out_size, void* d_ws, size_t ws_size,
                              hipStream_t stream) {
  const float* x  = (const float*)d_in[0];
  const float* rw = (const float*)d_in[1];
  const float* wg = (const float*)d_in[2];
  const float* wu = (const float*)d_in[3];
  const float* wd = (const float*)d_in[4];
  float* out    = (float*)d_out;
  float* logits = out + (size_t)N_TOK * D_;   // second output region

  char* ws = (char*)d_ws;
  int*   offs  = (int*)(ws + 64);
  unsigned short* zbuf = (unsigned short*)(ws + 256);       // 4KB zeros (plan writes)
  int*   sel   = (int*)  (ws + 4352);
  float* prob  = (float*)(ws + 37120);
  int*   ptok  = (int*)  (ws + 69888);
  float* pprob = (float*)(ws + 104704);
  unsigned short* Xb  = (unsigned short*)(ws + 172288);
  unsigned short* Wgb = Xb  + (size_t)N_TOK * D_;
  unsigned short* Wub = Wgb + WSZ;
  unsigned short* Wdb = Wub + WSZ;
  unsigned short* Hb  = Wdb + WSZ;                          // [CAP, I_] bf16

  hipMemsetAsync(d_out, 0, (size_t)N_TOK * D_ * 4, stream); // out accumulates via atomics

  convertw_kernel<<<dim3(WSZ / 4 / 256, 3), 256, 0, stream>>>(wg, wu, wd, Wgb);
  router_kernel<<<N_TOK / 4, 256, 0, stream>>>(x, rw, logits, sel, prob, Xb);
  plan_kernel<<<1, 1024, 0, stream>>>(sel, prob, offs, ptok, pprob, (unsigned int*)zbuf);
  gemm1_kernel<<<(CAP / BM) * (I_ / 64), 256, 0, stream>>>(Xb, Wgb, Wub, ptok, offs, zbuf, Hb);
  gemm2_kernel<<<(CAP / BM) * (D_ / 128), 256, 0, stream>>>(Hb, Wdb, ptok, pprob, offs, out);
}

// Round 5
// 107.562 us; speedup vs baseline: 1.7396x; 1.7396x over previous
//
#include <hip/hip_runtime.h>
#include <cstdint>

// Problem constants
#define N_TOK 4096   // B*T
#define D_    1024
#define E_    8
#define I_    512
#define KTOP  2
#define PAD   128    // expert segments padded to 128 (tile M)
#define BK    64     // K-step
#define CAP   (N_TOK*KTOP + E_*PAD)   // 9216 max padded positions
#define NBX   (CAP / PAD)             // 72 position tiles
#define WSZ   ((size_t)E_ * I_ * D_)  // one weight's element count

typedef __attribute__((ext_vector_type(4))) float f32x4;
typedef __attribute__((ext_vector_type(8))) short bf16x8;

__device__ inline unsigned short f2bf(float f) {
  union { float f; uint32_t u; } v; v.f = f;
  uint32_t r = v.u + 0x7fffu + ((v.u >> 16) & 1u);
  return (unsigned short)(r >> 16);
}

#define GLOAD_LDS16(gp, lp)                                                        \
  __builtin_amdgcn_global_load_lds((const __attribute__((address_space(1))) void*)(gp), \
                                   (__attribute__((address_space(3))) void*)(lp), 16, 0, 0)

// ---------------- fp32 -> bf16 convert: all 3 weights in one launch ----------------
__global__ __launch_bounds__(256) void convertw_kernel(const float* __restrict__ wg,
                                                       const float* __restrict__ wu,
                                                       const float* __restrict__ wd,
                                                       unsigned short* __restrict__ dst) {
  const int y = blockIdx.y;
  const float* s = (y == 0) ? wg : (y == 1) ? wu : wd;
  unsigned short* d = dst + (size_t)y * WSZ;
  int i = blockIdx.x * 256 + threadIdx.x;
  const float4 v = reinterpret_cast<const float4*>(s)[i];
  ushort4 o;
  o.x = f2bf(v.x); o.y = f2bf(v.y); o.z = f2bf(v.z); o.w = f2bf(v.w);
  reinterpret_cast<ushort4*>(d)[i] = o;
}

// ---------------- router: logits (fp32), top-2, softmax; fused x->bf16 ----------------
__global__ __launch_bounds__(256) void router_kernel(const float* __restrict__ x,
                                                     const float* __restrict__ rw,
                                                     float* __restrict__ logits,
                                                     int* __restrict__ sel,
                                                     float* __restrict__ prob,
                                                     unsigned short* __restrict__ Xb) {
  const int lane = threadIdx.x & 63;
  const int tok  = blockIdx.x * 4 + (threadIdx.x >> 6);
  const float4* xr = reinterpret_cast<const float4*>(x + (size_t)tok * D_);
  float4 xv[4];
#pragma unroll
  for (int q = 0; q < 4; ++q) xv[q] = xr[q * 64 + lane];
  float acc[E_];
#pragma unroll
  for (int e = 0; e < E_; ++e) {
    const float4* wr = reinterpret_cast<const float4*>(rw + (size_t)e * D_);
    float s = 0.f;
#pragma unroll
    for (int q = 0; q < 4; ++q) {
      float4 wv = wr[q * 64 + lane];
      s += xv[q].x * wv.x + xv[q].y * wv.y + xv[q].z * wv.z + xv[q].w * wv.w;
    }
    acc[e] = s;
  }
  ushort4* xb = reinterpret_cast<ushort4*>(Xb + (size_t)tok * D_);
#pragma unroll
  for (int q = 0; q < 4; ++q) {
    ushort4 o;
    o.x = f2bf(xv[q].x); o.y = f2bf(xv[q].y); o.z = f2bf(xv[q].z); o.w = f2bf(xv[q].w);
    xb[q * 64 + lane] = o;
  }
#pragma unroll
  for (int e = 0; e < E_; ++e)
#pragma unroll
    for (int off = 32; off; off >>= 1) acc[e] += __shfl_xor(acc[e], off);
  if (lane == 0) {
    float v0 = -1e30f, v1 = -1e30f; int i0 = 0, i1 = 0;
#pragma unroll
    for (int e = 0; e < E_; ++e) {
      float v = acc[e];
      logits[(size_t)tok * E_ + e] = v;
      if (v > v0)      { v1 = v0; i1 = i0; v0 = v; i0 = e; }
      else if (v > v1) { v1 = v;  i1 = e; }
    }
    float t  = __expf(v1 - v0);
    sel[tok * 2] = i0; sel[tok * 2 + 1] = i1;
    prob[tok * 2] = 1.f / (1.f + t);
    prob[tok * 2 + 1] = t / (1.f + t);
  }
}

// ---------------- plan: counts (ballot), padded offsets, scatter, pads, zbuf ----------------
__global__ __launch_bounds__(1024) void plan_kernel(const int* __restrict__ sel,
                                                    const float* __restrict__ prob,
                                                    int* __restrict__ offs,
                                                    int* __restrict__ ptok,
                                                    float* __restrict__ pprob,
                                                    int* __restrict__ tpos,
                                                    unsigned int* __restrict__ zbuf) {
  __shared__ int wcnt[16][E_];
  __shared__ int pfx[16][E_];
  __shared__ int soffs[E_ + 1];
  __shared__ int secnt[E_];
  const int tid = threadIdx.x;
  const int wave = tid >> 6, lane = tid & 63;
  const unsigned long long lt = (1ull << lane) - 1ull;

  zbuf[tid] = 0u;   // 4KB of zeros for gemm1 pad rows

  int   mye[8];
  int   mylp[8];
  float myp[8];
  int run[E_];
#pragma unroll
  for (int e = 0; e < E_; ++e) run[e] = 0;

#pragma unroll
  for (int it = 0; it < 8; ++it) {
    int i = wave * 512 + it * 64 + lane;
    int e = sel[i];
    mye[it] = e;
    myp[it] = prob[i];
    int lp = 0;
#pragma unroll
    for (int ee = 0; ee < E_; ++ee) {
      unsigned long long m = __ballot(e == ee);
      if (e == ee) lp = run[ee] + __popcll(m & lt);
      run[ee] += __popcll(m);
    }
    mylp[it] = lp;
  }
#pragma unroll
  for (int ee = 0; ee < E_; ++ee)
    if (lane == ee) wcnt[wave][ee] = run[ee];
  __syncthreads();

  if (tid == 0) {
    int ro = 0;
#pragma unroll
    for (int e = 0; e < E_; ++e) {
      int c = 0;
      int r = ro;
      for (int w = 0; w < 16; ++w) { pfx[w][e] = r; r += wcnt[w][e]; c += wcnt[w][e]; }
      soffs[e] = ro; offs[e] = ro; secnt[e] = c;
      ro += (c + PAD - 1) & ~(PAD - 1);
    }
    soffs[E_] = ro; offs[E_] = ro;
  }
  __syncthreads();

#pragma unroll
  for (int it = 0; it < 8; ++it) {
    int i = wave * 512 + it * 64 + lane;
    int pos = pfx[wave][mye[it]] + mylp[it];
    ptok[pos]  = i >> 1;
    pprob[pos] = myp[it];
    tpos[i]    = pos;
  }
  // fill padding slots (max 127 per expert)
#pragma unroll
  for (int e = 0; e < E_; ++e) {
    int s = soffs[e] + secnt[e];
    int npad = soffs[e + 1] - s;
    if (tid < npad) { ptok[s + tid] = -1; pprob[s + tid] = 0.f; }
  }
}

// ---------------- GEMM1: H = silu(X Wg^T) * (X Wu^T) ----------------
// 128pos x 64I tile, BK=64, single-buffered 32KB LDS (3 blocks/CU), m97 2-barrier loop.
__global__ __launch_bounds__(256) void gemm1_kernel(const unsigned short* __restrict__ Xb,
                                                    const unsigned short* __restrict__ Wg,
                                                    const unsigned short* __restrict__ Wu,
                                                    const int* __restrict__ ptok,
                                                    const int* __restrict__ offs,
                                                    const unsigned short* __restrict__ zbuf,
                                                    unsigned short* __restrict__ H) {
  __shared__ unsigned short As[PAD * BK];   // 16KB
  __shared__ unsigned short Bg[64 * BK];    // 8KB
  __shared__ unsigned short Bu[64 * BK];    // 8KB
  __shared__ int toks[PAD];

  // bijective XCD-chunked decode: 576 blocks = 72 per XCD, y-inner
  const int wgid = (blockIdx.x & 7) * 72 + (blockIdx.x >> 3);
  const int bx = wgid >> 3;          // 0..71 : position tile
  const int by = wgid & 7;           // 0..7  : I-panel (64 cols)

  const int total = offs[E_];
  const int t0 = bx * PAD;
  if (t0 >= total) return;
  int e = 0;
#pragma unroll
  for (int i = 1; i < E_; ++i) if (offs[i] <= t0) e = i;

  const int tid  = threadIdx.x;
  const int lane = tid & 63;
  const int w    = tid >> 6;
  if (tid < PAD) toks[tid] = ptok[t0 + tid];
  __syncthreads();

  const int ib    = by * 64;
  const int gcol8 = (lane & 7) ^ (lane >> 3);  // pre-swizzled source column (16B units)

  const unsigned short* asrc[4];
#pragma unroll
  for (int i = 0; i < 4; ++i) {
    int r = w * 32 + i * 8 + (lane >> 3);
    int t = toks[r];
    asrc[i] = (t >= 0) ? (Xb + (size_t)t * D_ + gcol8 * 8) : (zbuf + gcol8 * 8);
  }
  const unsigned short* bgsrc[2];
  const unsigned short* busrc[2];
#pragma unroll
  for (int i = 0; i < 2; ++i) {
    int r = w * 16 + i * 8 + (lane >> 3);
    size_t rowoff = ((size_t)e * I_ + ib + r) * D_ + gcol8 * 8;
    bgsrc[i] = Wg + rowoff;
    busrc[i] = Wu + rowoff;
  }

  f32x4 accg[4][2], accu[4][2];
#pragma unroll
  for (int m = 0; m < 4; ++m)
#pragma unroll
    for (int n = 0; n < 2; ++n) {
      accg[m][n] = (f32x4){0.f, 0.f, 0.f, 0.f};
      accu[m][n] = (f32x4){0.f, 0.f, 0.f, 0.f};
    }

  const int wr = w >> 1, wc = w & 1;   // wave grid: 2 (pos halves) x 2 (I halves)
  const int xr7 = lane & 7;

  for (int k0 = 0; k0 < D_; k0 += BK) {
#pragma unroll
    for (int i = 0; i < 4; ++i) GLOAD_LDS16(asrc[i] + k0, &As[(w * 4 + i) * 512]);
#pragma unroll
    for (int i = 0; i < 2; ++i) {
      GLOAD_LDS16(bgsrc[i] + k0, &Bg[(w * 2 + i) * 512]);
      GLOAD_LDS16(busrc[i] + k0, &Bu[(w * 2 + i) * 512]);
    }
    __syncthreads();   // drains vmcnt before barrier (compiler-inserted)
#pragma unroll
    for (int kk = 0; kk < 2; ++kk) {
      const int uoff = ((kk * 4 + (lane >> 4)) ^ xr7) * 8;
      bf16x8 a[4], bg[2], bu[2];
#pragma unroll
      for (int m = 0; m < 4; ++m) {
        int row = wr * 64 + m * 16 + (lane & 15);
        a[m] = *reinterpret_cast<const bf16x8*>(&As[row * BK + uoff]);
      }
#pragma unroll
      for (int n = 0; n < 2; ++n) {
        int row = wc * 32 + n * 16 + (lane & 15);
        bg[n] = *reinterpret_cast<const bf16x8*>(&Bg[row * BK + uoff]);
        bu[n] = *reinterpret_cast<const bf16x8*>(&Bu[row * BK + uoff]);
      }
#pragma unroll
      for (int m = 0; m < 4; ++m)
#pragma unroll
        for (int n = 0; n < 2; ++n) {
          accg[m][n] = __builtin_amdgcn_mfma_f32_16x16x32_bf16(bg[n], a[m], accg[m][n], 0, 0, 0);
          accu[m][n] = __builtin_amdgcn_mfma_f32_16x16x32_bf16(bu[n], a[m], accu[m][n], 0, 0, 0);
        }
    }
    __syncthreads();
  }

  // swapped-operand C/D layout: position = lane&15, I-index = (lane>>4)*4 + reg
#pragma unroll
  for (int m = 0; m < 4; ++m) {
    const int trow = wr * 64 + m * 16 + (lane & 15);
#pragma unroll
    for (int n = 0; n < 2; ++n) {
      const int icb = ib + wc * 32 + n * 16 + (lane >> 4) * 4;
      ushort4 st;
      float g, uu, h;
      g = accg[m][n][0]; uu = accu[m][n][0]; h = (g / (1.f + __expf(-g))) * uu; st.x = f2bf(h);
      g = accg[m][n][1]; uu = accu[m][n][1]; h = (g / (1.f + __expf(-g))) * uu; st.y = f2bf(h);
      g = accg[m][n][2]; uu = accu[m][n][2]; h = (g / (1.f + __expf(-g))) * uu; st.z = f2bf(h);
      g = accg[m][n][3]; uu = accu[m][n][3]; h = (g / (1.f + __expf(-g))) * uu; st.w = f2bf(h);
      *reinterpret_cast<ushort4*>(&H[(size_t)(t0 + trow) * I_ + icb]) = st;
    }
  }
}

// ---------------- GEMM2: Opos[pos] = prob * (H Wd^T) ----------------
// 128 x 128 tile, BK=64, single-buffered 32KB LDS (3 blocks/CU), plain float4 stores.
__global__ __launch_bounds__(256) void gemm2_kernel(const unsigned short* __restrict__ H,
                                                    const unsigned short* __restrict__ Wd,
                                                    const float* __restrict__ pprob,
                                                    const int* __restrict__ offs,
                                                    float* __restrict__ O) {
  __shared__ unsigned short As[PAD * BK];   // 16KB (H rows)
  __shared__ unsigned short Bs[PAD * BK];   // 16KB (Wd rows)
  __shared__ float probs[PAD];

  const int wgid = (blockIdx.x & 7) * 72 + (blockIdx.x >> 3);
  const int bx = wgid >> 3;          // 0..71 : position tile
  const int by = wgid & 7;           // 0..7  : D-panel (128 cols)

  const int total = offs[E_];
  const int t0 = bx * PAD;
  if (t0 >= total) return;
  int e = 0;
#pragma unroll
  for (int i = 1; i < E_; ++i) if (offs[i] <= t0) e = i;

  const int tid  = threadIdx.x;
  const int lane = tid & 63;
  const int w    = tid >> 6;
  if (tid < PAD) probs[tid] = pprob[t0 + tid];
  __syncthreads();

  const int db    = by * 128;
  const int gcol8 = (lane & 7) ^ (lane >> 3);

  const unsigned short* asrc[4];
  const unsigned short* bsrc[4];
#pragma unroll
  for (int i = 0; i < 4; ++i) {
    int r = w * 32 + i * 8 + (lane >> 3);
    asrc[i] = H + (size_t)(t0 + r) * I_ + gcol8 * 8;
    bsrc[i] = Wd + ((size_t)e * D_ + db + r) * I_ + gcol8 * 8;
  }

  f32x4 acc[4][4];
#pragma unroll
  for (int m = 0; m < 4; ++m)
#pragma unroll
    for (int n = 0; n < 4; ++n) acc[m][n] = (f32x4){0.f, 0.f, 0.f, 0.f};

  const int wr = w >> 1, wc = w & 1;   // wave grid: 2 (pos halves) x 2 (D halves)
  const int xr7 = lane & 7;

  for (int k0 = 0; k0 < I_; k0 += BK) {
#pragma unroll
    for (int i = 0; i < 4; ++i) {
      GLOAD_LDS16(asrc[i] + k0, &As[(w * 4 + i) * 512]);
      GLOAD_LDS16(bsrc[i] + k0, &Bs[(w * 4 + i) * 512]);
    }
    __syncthreads();
#pragma unroll
    for (int kk = 0; kk < 2; ++kk) {
      const int uoff = ((kk * 4 + (lane >> 4)) ^ xr7) * 8;
      bf16x8 a[4], b[4];
#pragma unroll
      for (int m = 0; m < 4; ++m) {
        int row = wr * 64 + m * 16 + (lane & 15);
        a[m] = *reinterpret_cast<const bf16x8*>(&As[row * BK + uoff]);
      }
#pragma unroll
      for (int n = 0; n < 4; ++n) {
        int row = wc * 64 + n * 16 + (lane & 15);
        b[n] = *reinterpret_cast<const bf16x8*>(&Bs[row * BK + uoff]);
      }
#pragma unroll
      for (int m = 0; m < 4; ++m)
#pragma unroll
        for (int n = 0; n < 4; ++n)
          acc[m][n] = __builtin_amdgcn_mfma_f32_16x16x32_bf16(b[n], a[m], acc[m][n], 0, 0, 0);
    }
    __syncthreads();
  }

#pragma unroll
  for (int m = 0; m < 4; ++m) {
    const int trow = wr * 64 + m * 16 + (lane & 15);
    const float p = probs[trow];
#pragma unroll
    for (int n = 0; n < 4; ++n) {
      const int dcb = db + wc * 64 + n * 16 + (lane >> 4) * 4;
      float4 v;
      v.x = acc[m][n][0] * p; v.y = acc[m][n][1] * p;
      v.z = acc[m][n][2] * p; v.w = acc[m][n][3] * p;
      *reinterpret_cast<float4*>(&O[(size_t)(t0 + trow) * D_ + dcb]) = v;
    }
  }
}

// ---------------- combine: out[t] = O[pos0] + O[pos1] ----------------
__global__ __launch_bounds__(256) void combine_kernel(const float* __restrict__ O,
                                                      const int* __restrict__ tpos,
                                                      float* __restrict__ out) {
  const int t = blockIdx.x;
  const int c = threadIdx.x;
  const int p0 = tpos[2 * t], p1 = tpos[2 * t + 1];
  const float4 a = reinterpret_cast<const float4*>(O + (size_t)p0 * D_)[c];
  const float4 b = reinterpret_cast<const float4*>(O + (size_t)p1 * D_)[c];
  float4 r;
  r.x = a.x + b.x; r.y = a.y + b.y; r.z = a.z + b.z; r.w = a.w + b.w;
  reinterpret_cast<float4*>(out + (size_t)t * D_)[c] = r;
}

extern "C" void kernel_launch(void* const* d_in, const int* in_sizes, int n_in,
                              void* d_out, int out_size, void* d_ws, size_t ws_size,
                              hipStream_t stream) {
  const float* x  = (const float*)d_in[0];
  const float* rw = (const float*)d_in[1];
  const float* wg = (const float*)d_in[2];
  const float* wu = (const float*)d_in[3];
  const float* wd = (const float*)d_in[4];
  float* out    = (float*)d_out;
  float* logits = out + (size_t)N_TOK * D_;   // second output region

  char* ws = (char*)d_ws;
  int*   offs  = (int*)(ws + 64);
  unsigned short* zbuf = (unsigned short*)(ws + 256);       // 4KB zeros (plan writes)
  int*   sel   = (int*)  (ws + 4352);
  float* prob  = (float*)(ws + 37120);
  int*   ptok  = (int*)  (ws + 69888);    // CAP ints
  float* pprob = (float*)(ws + 106752);   // CAP floats
  int*   tpos  = (int*)  (ws + 143616);   // 8192 ints
  unsigned short* Xb  = (unsigned short*)(ws + 176384);
  unsigned short* Wgb = Xb  + (size_t)N_TOK * D_;
  unsigned short* Wub = Wgb + WSZ;
  unsigned short* Wdb = Wub + WSZ;
  unsigned short* Hb  = Wdb + WSZ;                          // [CAP, I_] bf16
  float* Opos = (float*)(Hb + (size_t)CAP * I_);            // [CAP, D_] fp32

  convertw_kernel<<<dim3(WSZ / 4 / 256, 3), 256, 0, stream>>>(wg, wu, wd, Wgb);
  router_kernel<<<N_TOK / 4, 256, 0, stream>>>(x, rw, logits, sel, prob, Xb);
  plan_kernel<<<1, 1024, 0, stream>>>(sel, prob, offs, ptok, pprob, tpos, (unsigned int*)zbuf);
  gemm1_kernel<<<NBX * 8, 256, 0, stream>>>(Xb, Wgb, Wub, ptok, offs, zbuf, Hb);
  gemm2_kernel<<<NBX * 8, 256, 0, stream>>>(Hb, Wdb, pprob, offs, Opos);
  combine_kernel<<<N_TOK, 256, 0, stream>>>(Opos, tpos, out);
}

// Round 6
// 91.619 us; speedup vs baseline: 2.0423x; 1.1740x over previous
//
#include <hip/hip_runtime.h>
#include <cstdint>

// Problem constants
#define N_TOK 4096   // B*T
#define D_    1024
#define E_    8
#define I_    512
#define KTOP  2
#define PAD   64     // expert segments padded to 64 (tile M)
#define BK    64     // K-step
#define CAP   (N_TOK*KTOP + E_*PAD)   // 8704 max padded positions
#define NBX   (CAP / PAD)             // 136 position tiles (17 per XCD)
#define WSZ   ((size_t)E_ * I_ * D_)  // one weight's element count

typedef __attribute__((ext_vector_type(4))) float f32x4;
typedef __attribute__((ext_vector_type(8))) short bf16x8;

__device__ inline unsigned short f2bf(float f) {
  union { float f; uint32_t u; } v; v.f = f;
  uint32_t r = v.u + 0x7fffu + ((v.u >> 16) & 1u);
  return (unsigned short)(r >> 16);
}
__device__ inline float bf2f(unsigned short h) {
  union { uint32_t u; float f; } v; v.u = ((uint32_t)h) << 16;
  return v.f;
}

#define GLOAD_LDS16(gp, lp)                                                        \
  __builtin_amdgcn_global_load_lds((const __attribute__((address_space(1))) void*)(gp), \
                                   (__attribute__((address_space(3))) void*)(lp), 16, 0, 0)

// ---------------- fp32 -> bf16 convert: all 3 weights in one launch ----------------
__global__ __launch_bounds__(256) void convertw_kernel(const float* __restrict__ wg,
                                                       const float* __restrict__ wu,
                                                       const float* __restrict__ wd,
                                                       unsigned short* __restrict__ dst) {
  const int y = blockIdx.y;
  const float* s = (y == 0) ? wg : (y == 1) ? wu : wd;
  unsigned short* d = dst + (size_t)y * WSZ;
  int i = blockIdx.x * 256 + threadIdx.x;
  const float4 v = reinterpret_cast<const float4*>(s)[i];
  ushort4 o;
  o.x = f2bf(v.x); o.y = f2bf(v.y); o.z = f2bf(v.z); o.w = f2bf(v.w);
  reinterpret_cast<ushort4*>(d)[i] = o;
}

// ---------------- router: logits (fp32), top-2, softmax; fused x->bf16 ----------------
__global__ __launch_bounds__(256) void router_kernel(const float* __restrict__ x,
                                                     const float* __restrict__ rw,
                                                     float* __restrict__ logits,
                                                     int* __restrict__ sel,
                                                     float* __restrict__ prob,
                                                     unsigned short* __restrict__ Xb) {
  const int lane = threadIdx.x & 63;
  const int tok  = blockIdx.x * 4 + (threadIdx.x >> 6);
  const float4* xr = reinterpret_cast<const float4*>(x + (size_t)tok * D_);
  float4 xv[4];
#pragma unroll
  for (int q = 0; q < 4; ++q) xv[q] = xr[q * 64 + lane];
  float acc[E_];
#pragma unroll
  for (int e = 0; e < E_; ++e) {
    const float4* wr = reinterpret_cast<const float4*>(rw + (size_t)e * D_);
    float s = 0.f;
#pragma unroll
    for (int q = 0; q < 4; ++q) {
      float4 wv = wr[q * 64 + lane];
      s += xv[q].x * wv.x + xv[q].y * wv.y + xv[q].z * wv.z + xv[q].w * wv.w;
    }
    acc[e] = s;
  }
  ushort4* xb = reinterpret_cast<ushort4*>(Xb + (size_t)tok * D_);
#pragma unroll
  for (int q = 0; q < 4; ++q) {
    ushort4 o;
    o.x = f2bf(xv[q].x); o.y = f2bf(xv[q].y); o.z = f2bf(xv[q].z); o.w = f2bf(xv[q].w);
    xb[q * 64 + lane] = o;
  }
#pragma unroll
  for (int e = 0; e < E_; ++e)
#pragma unroll
    for (int off = 32; off; off >>= 1) acc[e] += __shfl_xor(acc[e], off);
  if (lane == 0) {
    float v0 = -1e30f, v1 = -1e30f; int i0 = 0, i1 = 0;
#pragma unroll
    for (int e = 0; e < E_; ++e) {
      float v = acc[e];
      logits[(size_t)tok * E_ + e] = v;
      if (v > v0)      { v1 = v0; i1 = i0; v0 = v; i0 = e; }
      else if (v > v1) { v1 = v;  i1 = e; }
    }
    float t  = __expf(v1 - v0);
    sel[tok * 2] = i0; sel[tok * 2 + 1] = i1;
    prob[tok * 2] = 1.f / (1.f + t);
    prob[tok * 2 + 1] = t / (1.f + t);
  }
}

// ---------------- plan: counts (ballot), padded offsets, scatter, pads, zbuf ----------------
__global__ __launch_bounds__(1024) void plan_kernel(const int* __restrict__ sel,
                                                    const float* __restrict__ prob,
                                                    int* __restrict__ offs,
                                                    int* __restrict__ ptok,
                                                    float* __restrict__ pprob,
                                                    int* __restrict__ tpos,
                                                    unsigned int* __restrict__ zbuf) {
  __shared__ int wcnt[16][E_];
  __shared__ int pfx[16][E_];
  __shared__ int soffs[E_ + 1];
  __shared__ int secnt[E_];
  const int tid = threadIdx.x;
  const int wave = tid >> 6, lane = tid & 63;
  const unsigned long long lt = (1ull << lane) - 1ull;

  zbuf[tid] = 0u;   // 4KB of zeros for gemm1 pad rows

  int   mye[8];
  int   mylp[8];
  float myp[8];
  int run[E_];
#pragma unroll
  for (int e = 0; e < E_; ++e) run[e] = 0;

#pragma unroll
  for (int it = 0; it < 8; ++it) {
    int i = wave * 512 + it * 64 + lane;
    int e = sel[i];
    mye[it] = e;
    myp[it] = prob[i];
    int lp = 0;
#pragma unroll
    for (int ee = 0; ee < E_; ++ee) {
      unsigned long long m = __ballot(e == ee);
      if (e == ee) lp = run[ee] + __popcll(m & lt);
      run[ee] += __popcll(m);
    }
    mylp[it] = lp;
  }
#pragma unroll
  for (int ee = 0; ee < E_; ++ee)
    if (lane == ee) wcnt[wave][ee] = run[ee];
  __syncthreads();

  if (tid == 0) {
    int ro = 0;
#pragma unroll
    for (int e = 0; e < E_; ++e) {
      int c = 0;
      int r = ro;
      for (int w = 0; w < 16; ++w) { pfx[w][e] = r; r += wcnt[w][e]; c += wcnt[w][e]; }
      soffs[e] = ro; offs[e] = ro; secnt[e] = c;
      ro += (c + PAD - 1) & ~(PAD - 1);
    }
    soffs[E_] = ro; offs[E_] = ro;
  }
  __syncthreads();

#pragma unroll
  for (int it = 0; it < 8; ++it) {
    int i = wave * 512 + it * 64 + lane;
    int pos = pfx[wave][mye[it]] + mylp[it];
    ptok[pos]  = i >> 1;
    pprob[pos] = myp[it];
    tpos[i]    = pos;
  }
  // fill padding slots (max 63 per expert)
#pragma unroll
  for (int e = 0; e < E_; ++e) {
    int s = soffs[e] + secnt[e];
    int npad = soffs[e + 1] - s;
    if (tid < npad) { ptok[s + tid] = -1; pprob[s + tid] = 0.f; }
  }
}

// ---------------- GEMM1: H = silu(X Wg^T) * (X Wu^T) ----------------
// 64pos x 64I tile, BK=64, single-buffered 24KB LDS, 1088 blocks (4.25/CU).
__global__ __launch_bounds__(256, 4) void gemm1_kernel(const unsigned short* __restrict__ Xb,
                                                       const unsigned short* __restrict__ Wg,
                                                       const unsigned short* __restrict__ Wu,
                                                       const int* __restrict__ ptok,
                                                       const int* __restrict__ offs,
                                                       const unsigned short* __restrict__ zbuf,
                                                       unsigned short* __restrict__ H) {
  __shared__ unsigned short As[PAD * BK];   // 8KB
  __shared__ unsigned short Bg[64 * BK];    // 8KB
  __shared__ unsigned short Bu[64 * BK];    // 8KB
  __shared__ int toks[PAD];

  // bijective XCD-chunked decode: 1088 blocks = 136 per XCD (17 bx x 8 by), y-inner
  const int wgid = (blockIdx.x & 7) * 136 + (blockIdx.x >> 3);
  const int bx = wgid >> 3;          // 0..135 : position tile
  const int by = wgid & 7;           // 0..7   : I-panel (64 cols)

  const int total = offs[E_];
  const int t0 = bx * PAD;
  if (t0 >= total) return;
  int e = 0;
#pragma unroll
  for (int i = 1; i < E_; ++i) if (offs[i] <= t0) e = i;

  const int tid  = threadIdx.x;
  const int lane = tid & 63;
  const int w    = tid >> 6;
  if (tid < PAD) toks[tid] = ptok[t0 + tid];
  __syncthreads();

  const int ib    = by * 64;
  const int gcol8 = (lane & 7) ^ (lane >> 3);  // pre-swizzled source column (16B units)

  const unsigned short* asrc[2];
  const unsigned short* bgsrc[2];
  const unsigned short* busrc[2];
#pragma unroll
  for (int i = 0; i < 2; ++i) {
    int r = w * 16 + i * 8 + (lane >> 3);
    int t = toks[r];
    asrc[i] = (t >= 0) ? (Xb + (size_t)t * D_ + gcol8 * 8) : (zbuf + gcol8 * 8);
    size_t rowoff = ((size_t)e * I_ + ib + r) * D_ + gcol8 * 8;
    bgsrc[i] = Wg + rowoff;
    busrc[i] = Wu + rowoff;
  }

  f32x4 accg[2][2], accu[2][2];
#pragma unroll
  for (int m = 0; m < 2; ++m)
#pragma unroll
    for (int n = 0; n < 2; ++n) {
      accg[m][n] = (f32x4){0.f, 0.f, 0.f, 0.f};
      accu[m][n] = (f32x4){0.f, 0.f, 0.f, 0.f};
    }

  const int wr = w >> 1, wc = w & 1;   // wave grid: 2 (pos halves) x 2 (I halves)
  const int xr7 = lane & 7;

  for (int k0 = 0; k0 < D_; k0 += BK) {
#pragma unroll
    for (int i = 0; i < 2; ++i) {
      GLOAD_LDS16(asrc[i] + k0, &As[(w * 2 + i) * 512]);
      GLOAD_LDS16(bgsrc[i] + k0, &Bg[(w * 2 + i) * 512]);
      GLOAD_LDS16(busrc[i] + k0, &Bu[(w * 2 + i) * 512]);
    }
    __syncthreads();   // compiler drains vmcnt before barrier
#pragma unroll
    for (int kk = 0; kk < 2; ++kk) {
      const int uoff = ((kk * 4 + (lane >> 4)) ^ xr7) * 8;
      bf16x8 a[2], bg[2], bu[2];
#pragma unroll
      for (int m = 0; m < 2; ++m) {
        int row = wr * 32 + m * 16 + (lane & 15);
        a[m] = *reinterpret_cast<const bf16x8*>(&As[row * BK + uoff]);
      }
#pragma unroll
      for (int n = 0; n < 2; ++n) {
        int row = wc * 32 + n * 16 + (lane & 15);
        bg[n] = *reinterpret_cast<const bf16x8*>(&Bg[row * BK + uoff]);
        bu[n] = *reinterpret_cast<const bf16x8*>(&Bu[row * BK + uoff]);
      }
#pragma unroll
      for (int m = 0; m < 2; ++m)
#pragma unroll
        for (int n = 0; n < 2; ++n) {
          accg[m][n] = __builtin_amdgcn_mfma_f32_16x16x32_bf16(bg[n], a[m], accg[m][n], 0, 0, 0);
          accu[m][n] = __builtin_amdgcn_mfma_f32_16x16x32_bf16(bu[n], a[m], accu[m][n], 0, 0, 0);
        }
    }
    __syncthreads();
  }

  // swapped-operand C/D layout: position = lane&15, I-index = (lane>>4)*4 + reg
#pragma unroll
  for (int m = 0; m < 2; ++m) {
    const int trow = wr * 32 + m * 16 + (lane & 15);
#pragma unroll
    for (int n = 0; n < 2; ++n) {
      const int icb = ib + wc * 32 + n * 16 + (lane >> 4) * 4;
      ushort4 st;
      float g, uu, h;
      g = accg[m][n][0]; uu = accu[m][n][0]; h = (g / (1.f + __expf(-g))) * uu; st.x = f2bf(h);
      g = accg[m][n][1]; uu = accu[m][n][1]; h = (g / (1.f + __expf(-g))) * uu; st.y = f2bf(h);
      g = accg[m][n][2]; uu = accu[m][n][2]; h = (g / (1.f + __expf(-g))) * uu; st.z = f2bf(h);
      g = accg[m][n][3]; uu = accu[m][n][3]; h = (g / (1.f + __expf(-g))) * uu; st.w = f2bf(h);
      *reinterpret_cast<ushort4*>(&H[(size_t)(t0 + trow) * I_ + icb]) = st;
    }
  }
}

// ---------------- GEMM2: Opos[pos] = prob * (H Wd^T), bf16 out ----------------
// 64pos x 128D tile, BK=64, single-buffered 24KB LDS, 1088 blocks (4.25/CU).
__global__ __launch_bounds__(256, 4) void gemm2_kernel(const unsigned short* __restrict__ H,
                                                       const unsigned short* __restrict__ Wd,
                                                       const float* __restrict__ pprob,
                                                       const int* __restrict__ offs,
                                                       unsigned short* __restrict__ O) {
  __shared__ unsigned short As[PAD * BK];   // 8KB (H rows)
  __shared__ unsigned short Bs[128 * BK];   // 16KB (Wd rows)
  __shared__ float probs[PAD];

  const int wgid = (blockIdx.x & 7) * 136 + (blockIdx.x >> 3);
  const int bx = wgid >> 3;          // 0..135 : position tile
  const int by = wgid & 7;           // 0..7   : D-panel (128 cols)

  const int total = offs[E_];
  const int t0 = bx * PAD;
  if (t0 >= total) return;
  int e = 0;
#pragma unroll
  for (int i = 1; i < E_; ++i) if (offs[i] <= t0) e = i;

  const int tid  = threadIdx.x;
  const int lane = tid & 63;
  const int w    = tid >> 6;
  if (tid < PAD) probs[tid] = pprob[t0 + tid];
  __syncthreads();

  const int db    = by * 128;
  const int gcol8 = (lane & 7) ^ (lane >> 3);

  const unsigned short* asrc[2];
#pragma unroll
  for (int i = 0; i < 2; ++i) {
    int r = w * 16 + i * 8 + (lane >> 3);
    asrc[i] = H + (size_t)(t0 + r) * I_ + gcol8 * 8;
  }
  const unsigned short* bsrc[4];
#pragma unroll
  for (int i = 0; i < 4; ++i) {
    int r = w * 32 + i * 8 + (lane >> 3);
    bsrc[i] = Wd + ((size_t)e * D_ + db + r) * I_ + gcol8 * 8;
  }

  f32x4 acc[2][4];
#pragma unroll
  for (int m = 0; m < 2; ++m)
#pragma unroll
    for (int n = 0; n < 4; ++n) acc[m][n] = (f32x4){0.f, 0.f, 0.f, 0.f};

  const int wr = w >> 1, wc = w & 1;   // wave grid: 2 (pos halves) x 2 (D halves)
  const int xr7 = lane & 7;

  for (int k0 = 0; k0 < I_; k0 += BK) {
#pragma unroll
    for (int i = 0; i < 2; ++i) GLOAD_LDS16(asrc[i] + k0, &As[(w * 2 + i) * 512]);
#pragma unroll
    for (int i = 0; i < 4; ++i) GLOAD_LDS16(bsrc[i] + k0, &Bs[(w * 4 + i) * 512]);
    __syncthreads();
#pragma unroll
    for (int kk = 0; kk < 2; ++kk) {
      const int uoff = ((kk * 4 + (lane >> 4)) ^ xr7) * 8;
      bf16x8 a[2], b[4];
#pragma unroll
      for (int m = 0; m < 2; ++m) {
        int row = wr * 32 + m * 16 + (lane & 15);
        a[m] = *reinterpret_cast<const bf16x8*>(&As[row * BK + uoff]);
      }
#pragma unroll
      for (int n = 0; n < 4; ++n) {
        int row = wc * 64 + n * 16 + (lane & 15);
        b[n] = *reinterpret_cast<const bf16x8*>(&Bs[row * BK + uoff]);
      }
#pragma unroll
      for (int m = 0; m < 2; ++m)
#pragma unroll
        for (int n = 0; n < 4; ++n)
          acc[m][n] = __builtin_amdgcn_mfma_f32_16x16x32_bf16(b[n], a[m], acc[m][n], 0, 0, 0);
    }
    __syncthreads();
  }

#pragma unroll
  for (int m = 0; m < 2; ++m) {
    const int trow = wr * 32 + m * 16 + (lane & 15);
    const float p = probs[trow];
#pragma unroll
    for (int n = 0; n < 4; ++n) {
      const int dcb = db + wc * 64 + n * 16 + (lane >> 4) * 4;
      ushort4 v;
      v.x = f2bf(acc[m][n][0] * p); v.y = f2bf(acc[m][n][1] * p);
      v.z = f2bf(acc[m][n][2] * p); v.w = f2bf(acc[m][n][3] * p);
      *reinterpret_cast<ushort4*>(&O[(size_t)(t0 + trow) * D_ + dcb]) = v;
    }
  }
}

// ---------------- combine: out[t] = O[pos0] + O[pos1] (bf16 in, fp32 out) ----------------
__global__ __launch_bounds__(256) void combine_kernel(const unsigned short* __restrict__ O,
                                                      const int* __restrict__ tpos,
                                                      float* __restrict__ out) {
  const int t = blockIdx.x;
  const int c = threadIdx.x;
  const int p0 = tpos[2 * t], p1 = tpos[2 * t + 1];
  const ushort4 a = reinterpret_cast<const ushort4*>(O + (size_t)p0 * D_)[c];
  const ushort4 b = reinterpret_cast<const ushort4*>(O + (size_t)p1 * D_)[c];
  float4 r;
  r.x = bf2f(a.x) + bf2f(b.x); r.y = bf2f(a.y) + bf2f(b.y);
  r.z = bf2f(a.z) + bf2f(b.z); r.w = bf2f(a.w) + bf2f(b.w);
  reinterpret_cast<float4*>(out + (size_t)t * D_)[c] = r;
}

extern "C" void kernel_launch(void* const* d_in, const int* in_sizes, int n_in,
                              void* d_out, int out_size, void* d_ws, size_t ws_size,
                              hipStream_t stream) {
  const float* x  = (const float*)d_in[0];
  const float* rw = (const float*)d_in[1];
  const float* wg = (const float*)d_in[2];
  const float* wu = (const float*)d_in[3];
  const float* wd = (const float*)d_in[4];
  float* out    = (float*)d_out;
  float* logits = out + (size_t)N_TOK * D_;   // second output region

  char* ws = (char*)d_ws;
  int*   offs  = (int*)(ws + 64);
  unsigned short* zbuf = (unsigned short*)(ws + 256);       // 4KB zeros (plan writes)
  int*   sel   = (int*)  (ws + 4352);
  float* prob  = (float*)(ws + 37120);
  int*   ptok  = (int*)  (ws + 69888);    // CAP ints  -> ends 104704
  float* pprob = (float*)(ws + 104704);   // CAP floats -> ends 139520
  int*   tpos  = (int*)  (ws + 139520);   // 8192 ints  -> ends 172288
  unsigned short* Xb  = (unsigned short*)(ws + 172288);
  unsigned short* Wgb = Xb  + (size_t)N_TOK * D_;
  unsigned short* Wub = Wgb + WSZ;
  unsigned short* Wdb = Wub + WSZ;
  unsigned short* Hb  = Wdb + WSZ;                          // [CAP, I_] bf16
  unsigned short* Opos = Hb + (size_t)CAP * I_;             // [CAP, D_] bf16

  convertw_kernel<<<dim3(WSZ / 4 / 256, 3), 256, 0, stream>>>(wg, wu, wd, Wgb);
  router_kernel<<<N_TOK / 4, 256, 0, stream>>>(x, rw, logits, sel, prob, Xb);
  plan_kernel<<<1, 1024, 0, stream>>>(sel, prob, offs, ptok, pprob, tpos, (unsigned int*)zbuf);
  gemm1_kernel<<<NBX * 8, 256, 0, stream>>>(Xb, Wgb, Wub, ptok, offs, zbuf, Hb);
  gemm2_kernel<<<NBX * 8, 256, 0, stream>>>(Hb, Wdb, pprob, offs, Opos);
  combine_kernel<<<N_TOK, 256, 0, stream>>>(Opos, tpos, out);
}